// Round 3
// baseline (275.697 us; speedup 1.0000x reference)
//
#include <hip/hip_runtime.h>
#include <hip/hip_bf16.h>
#include <stdint.h>

#define NTOK 49
#define DIM  128
#define NH   4
#define QKVN 384
#define SCALE 0.17677669529663687f

typedef __bf16 bfloat_t;
typedef bfloat_t bf16x8 __attribute__((ext_vector_type(8)));
typedef bfloat_t bf16x4 __attribute__((ext_vector_type(4)));
typedef float f32x4 __attribute__((ext_vector_type(4)));

static __device__ __forceinline__ bf16x8 cvt8(f32x4 lo, f32x4 hi) {
    bf16x8 r;
    r[0] = (bfloat_t)lo[0]; r[1] = (bfloat_t)lo[1]; r[2] = (bfloat_t)lo[2]; r[3] = (bfloat_t)lo[3];
    r[4] = (bfloat_t)hi[0]; r[5] = (bfloat_t)hi[1]; r[6] = (bfloat_t)hi[2]; r[7] = (bfloat_t)hi[3];
    return r;
}

__global__ void prep_weights(const float* __restrict__ qkvw,
                             const float* __restrict__ projw,
                             bfloat_t* __restrict__ qkvw_b,
                             bfloat_t* __restrict__ projw_b) {
    int i = blockIdx.x * 256 + threadIdx.x;
    if (i < QKVN * DIM) qkvw_b[i] = (bfloat_t)qkvw[i];
    if (i < DIM * DIM)  projw_b[i] = (bfloat_t)projw[i];
}

// cmb[w][h][tok_q(64)][tok_k(64)] = bias + mask; tok_k>=49 -> -1e30; tok_q>=49 -> 0
__global__ void prep_cmb(const float* __restrict__ mask,
                         const float* __restrict__ bias_table,
                         const int* __restrict__ rel_index,
                         float* __restrict__ cmb) {
    int wh = blockIdx.x;            // w*NH + h
    int w = wh >> 2, h = wh & 3;
    for (int idx = threadIdx.x; idx < 4096; idx += 256) {
        int row = idx >> 6, col = idx & 63;   // row=tok_q, col=tok_k
        float v;
        if (col >= NTOK)      v = -1e30f;
        else if (row >= NTOK) v = 0.f;
        else v = bias_table[rel_index[row * NTOK + col] * NH + h]
               + mask[(w * NTOK + row) * NTOK + col];
        cmb[(size_t)wh * 4096 + idx] = v;
    }
}

// ================= K1: big QKV GEMM, no LDS, no barriers =================
// Block = 128 rows (2 windows, tok 64-padded) x 128 cols (one qkv type, bn).
// Writes q,k row-major [w][h][tok64][32] (q pre-scaled), vT [w][h][32][tok64].
// Pad rows (tok>=49) get bias values -- harmless: killed by cmb -1e30 / P==0 in K2.
__global__ __launch_bounds__(256, 4)
void qkv_gemm(const float* __restrict__ x,
              const float* __restrict__ qkv_b,
              const bfloat_t* __restrict__ qkvw,
              bfloat_t* __restrict__ qg,
              bfloat_t* __restrict__ kg,
              bfloat_t* __restrict__ vtg) {
    const int bn = blockIdx.x;          // 0=q 1=k 2=v  (fast dim: x reuse via L3)
    const int bm = blockIdx.y;          // window pair
    const int tid = threadIdx.x;
    const int wave = tid >> 6, lane = tid & 63;
    const int g = lane >> 4, c = lane & 15;
    const int w = bm * 2 + (wave >> 1); // window (wave-uniform)
    const int nh0 = (wave & 1) * 64;    // col half within the 128-col type block

    f32x4 acc[4][4];
    #pragma unroll
    for (int nt = 0; nt < 4; ++nt) {
        const float bias = qkv_b[bn * 128 + nh0 + nt * 16 + c];
        #pragma unroll
        for (int mt = 0; mt < 4; ++mt) acc[mt][nt] = (f32x4){bias, bias, bias, bias};
    }
    const float* xw = x + (size_t)w * (NTOK * DIM);
    #pragma unroll
    for (int ks = 0; ks < 4; ++ks) {
        bf16x8 af[4], bfr[4];
        #pragma unroll
        for (int mt = 0; mt < 4; ++mt) {
            const int tok = mt * 16 + c;          // 0..63; only mt==3,c>=1 invalid
            if (tok < NTOK) {
                const float* rp = xw + tok * DIM + ks * 32 + g * 8;
                af[mt] = cvt8(*(const f32x4*)rp, *(const f32x4*)(rp + 4));
            } else {
                af[mt] = cvt8((f32x4){0.f,0.f,0.f,0.f}, (f32x4){0.f,0.f,0.f,0.f});
            }
        }
        #pragma unroll
        for (int nt = 0; nt < 4; ++nt)
            bfr[nt] = *(const bf16x8*)(qkvw + (size_t)(bn * 128 + nh0 + nt * 16 + c) * DIM + ks * 32 + g * 8);
        #pragma unroll
        for (int mt = 0; mt < 4; ++mt)
            #pragma unroll
            for (int nt = 0; nt < 4; ++nt)
                acc[mt][nt] = __builtin_amdgcn_mfma_f32_16x16x32_bf16(af[mt], bfr[nt], acc[mt][nt], 0, 0, 0);
    }
    // C/D layout: col = n = c, rows = m = mt*16 + g*4 + r (= tok, consecutive in r)
    if (bn == 2) {
        #pragma unroll
        for (int nt = 0; nt < 4; ++nt) {
            const int n = nh0 + nt * 16 + c;
            bfloat_t* base = vtg + (((size_t)w * NH + (n >> 5)) * 32 + (n & 31)) * 64;
            #pragma unroll
            for (int mt = 0; mt < 4; ++mt) {
                const f32x4 a = acc[mt][nt];
                bf16x4 pk = { (bfloat_t)a[0], (bfloat_t)a[1], (bfloat_t)a[2], (bfloat_t)a[3] };
                *(bf16x4*)(base + mt * 16 + g * 4) = pk;   // 4 consecutive tok
            }
        }
    } else {
        bfloat_t* dst = (bn == 0) ? qg : kg;
        const float sc = (bn == 0) ? SCALE : 1.f;
        #pragma unroll
        for (int nt = 0; nt < 4; ++nt) {
            const int n = nh0 + nt * 16 + c;
            bfloat_t* base = dst + ((size_t)w * NH + (n >> 5)) * (64 * 32) + (n & 31);
            #pragma unroll
            for (int mt = 0; mt < 4; ++mt) {
                const f32x4 a = acc[mt][nt];
                #pragma unroll
                for (int r = 0; r < 4; ++r)
                    base[(mt * 16 + g * 4 + r) * 32] = (bfloat_t)(a[r] * sc);
            }
        }
    }
}

// ================= K2: per-window attn + proj (frags direct from global) ====
// LDS: P per wave [64tq][64tk] bf16 swizzled, 8 KB * 4 = 32 KB; ao overlays [0,16K).
__global__ __launch_bounds__(256, 4)
void attn_proj(const bfloat_t* __restrict__ qg,
               const bfloat_t* __restrict__ kg,
               const bfloat_t* __restrict__ vtg,
               const float* __restrict__ proj_b,
               const bfloat_t* __restrict__ projw,
               const float* __restrict__ cmb,
               float* __restrict__ out, int nw) {
    __shared__ __align__(16) char smem[32768];
    const int b = blockIdx.x;
    const int tid = threadIdx.x;
    const int wave = tid >> 6, lane = tid & 63;
    const int g = lane >> 4, c = lane & 15;
    const int h = wave;
    char* Pp = smem + wave * 8192;

    const bfloat_t* qb_ = qg + ((size_t)b * NH + h) * (64 * 32);
    const bfloat_t* kb_ = kg + ((size_t)b * NH + h) * (64 * 32);
    const bfloat_t* vb_ = vtg + ((size_t)b * NH + h) * (32 * 64);

    // ---- S^T = k . q^T with C-init = cmb^T; softmax over tok_k ----
    float dinv[4];
    {
        bf16x8 qf[4], kf[4];
        #pragma unroll
        for (int t = 0; t < 4; ++t) {
            qf[t] = *(const bf16x8*)(qb_ + (t * 16 + c) * 32 + g * 8);
            kf[t] = *(const bf16x8*)(kb_ + (t * 16 + c) * 32 + g * 8);
        }
        const float* cw = cmb + (size_t)((b % nw) * NH + h) * 4096;
        f32x4 s[4][4];
        #pragma unroll
        for (int mtk = 0; mtk < 4; ++mtk)
            #pragma unroll
            for (int ntq = 0; ntq < 4; ++ntq)
                s[mtk][ntq] = *(const f32x4*)(cw + (ntq * 16 + c) * 64 + mtk * 16 + g * 4);
        #pragma unroll
        for (int mtk = 0; mtk < 4; ++mtk)
            #pragma unroll
            for (int ntq = 0; ntq < 4; ++ntq)
                s[mtk][ntq] = __builtin_amdgcn_mfma_f32_16x16x32_bf16(kf[mtk], qf[ntq], s[mtk][ntq], 0, 0, 0);

        #pragma unroll
        for (int ntq = 0; ntq < 4; ++ntq) {
            float m = s[0][ntq][0];
            #pragma unroll
            for (int mtk = 0; mtk < 4; ++mtk)
                #pragma unroll
                for (int r = 0; r < 4; ++r) m = fmaxf(m, s[mtk][ntq][r]);
            m = fmaxf(m, __shfl_xor(m, 16));
            m = fmaxf(m, __shfl_xor(m, 32));
            float sum = 0.f;
            #pragma unroll
            for (int mtk = 0; mtk < 4; ++mtk)
                #pragma unroll
                for (int r = 0; r < 4; ++r) {
                    float p = __expf(s[mtk][ntq][r] - m);
                    s[mtk][ntq][r] = p;
                    sum += p;
                }
            sum += __shfl_xor(sum, 16);
            sum += __shfl_xor(sum, 32);
            dinv[ntq] = 1.f / sum;
        }
        // P[tok_q][tok_k] bf16, XOR-swizzled granules
        #pragma unroll
        for (int mtk = 0; mtk < 4; ++mtk)
            #pragma unroll
            for (int ntq = 0; ntq < 4; ++ntq) {
                const f32x4 a = s[mtk][ntq];
                bf16x4 pk = { (bfloat_t)a[0], (bfloat_t)a[1], (bfloat_t)a[2], (bfloat_t)a[3] };
                const int byte = (ntq*16 + c)*128 + (((2*mtk + (g>>1)) ^ (c&7)) << 4) + ((g&1) << 3);
                *(bf16x4*)(Pp + byte) = pk;
            }
    }

    // ---- O^T = vT . P^T ----
    {
        f32x4 o[2][4];
        #pragma unroll
        for (int mtd = 0; mtd < 2; ++mtd)
            #pragma unroll
            for (int ntq = 0; ntq < 4; ++ntq) o[mtd][ntq] = (f32x4){0.f,0.f,0.f,0.f};
        #pragma unroll
        for (int ks = 0; ks < 2; ++ks) {
            bf16x8 vf[2], pf[4];
            #pragma unroll
            for (int mtd = 0; mtd < 2; ++mtd)
                vf[mtd] = *(const bf16x8*)(vb_ + (mtd * 16 + c) * 64 + ks * 32 + g * 8);
            #pragma unroll
            for (int ntq = 0; ntq < 4; ++ntq)
                pf[ntq] = *(const bf16x8*)(Pp + (ntq*16 + c)*128 + (((ks*4 + g) ^ (c&7)) << 4));
            #pragma unroll
            for (int mtd = 0; mtd < 2; ++mtd)
                #pragma unroll
                for (int ntq = 0; ntq < 4; ++ntq)
                    o[mtd][ntq] = __builtin_amdgcn_mfma_f32_16x16x32_bf16(vf[mtd], pf[ntq], o[mtd][ntq], 0, 0, 0);
        }
        #pragma unroll
        for (int mtd = 0; mtd < 2; ++mtd)
            #pragma unroll
            for (int ntq = 0; ntq < 4; ++ntq)
                #pragma unroll
                for (int r = 0; r < 4; ++r) o[mtd][ntq][r] *= dinv[ntq];

        __syncthreads();   // all waves done reading their P before ao overlays [0,16K)
        #pragma unroll
        for (int mtd = 0; mtd < 2; ++mtd)
            #pragma unroll
            for (int ntq = 0; ntq < 4; ++ntq) {
                const f32x4 a = o[mtd][ntq];
                bf16x4 pk = { (bfloat_t)a[0], (bfloat_t)a[1], (bfloat_t)a[2], (bfloat_t)a[3] };
                const int byte = (ntq*16 + c)*256 + ((((h*4 + 2*mtd + (g>>1)) ^ c) & 15) << 4) + ((g&1) << 3);
                *(bf16x4*)(smem + byte) = pk;
            }
    }
    __syncthreads();

    // ---- out^T = Wp . ao^T ----
    {
        f32x4 po[2][4];
        #pragma unroll
        for (int mtO = 0; mtO < 2; ++mtO) {
            const f32x4 pb4 = *(const f32x4*)(proj_b + wave * 32 + mtO * 16 + g * 4);
            #pragma unroll
            for (int nt = 0; nt < 4; ++nt) po[mtO][nt] = pb4;
        }
        #pragma unroll
        for (int ks = 0; ks < 4; ++ks) {
            bf16x8 w0 = *(const bf16x8*)(projw + (wave * 32 +  0 + c) * DIM + ks * 32 + g * 8);
            bf16x8 w1 = *(const bf16x8*)(projw + (wave * 32 + 16 + c) * DIM + ks * 32 + g * 8);
            bf16x8 aof[4];
            #pragma unroll
            for (int nt = 0; nt < 4; ++nt)
                aof[nt] = *(const bf16x8*)(smem + (nt*16 + c)*256 + ((((ks*4 + g) ^ c) & 15) << 4));
            #pragma unroll
            for (int nt = 0; nt < 4; ++nt) {
                po[0][nt] = __builtin_amdgcn_mfma_f32_16x16x32_bf16(w0, aof[nt], po[0][nt], 0, 0, 0);
                po[1][nt] = __builtin_amdgcn_mfma_f32_16x16x32_bf16(w1, aof[nt], po[1][nt], 0, 0, 0);
            }
        }
        float* og = out + (size_t)b * (NTOK * DIM);
        #pragma unroll
        for (int nt = 0; nt < 4; ++nt) {
            const int tok = nt * 16 + c;
            if (tok < NTOK) {
                #pragma unroll
                for (int mtO = 0; mtO < 2; ++mtO)
                    *(f32x4*)(og + tok * DIM + wave * 32 + mtO * 16 + g * 4) = po[mtO][nt];
            }
        }
    }
}

// ================= Fallback: R2's fused kernel (passed) =====================
__global__ __launch_bounds__(256, 3)
void win_attn_fused(const float* __restrict__ x,
                    const float* __restrict__ qkv_b,
                    const float* __restrict__ proj_b,
                    const bfloat_t* __restrict__ qkvw,
                    const bfloat_t* __restrict__ projw,
                    const float* __restrict__ cmb,
                    float* __restrict__ out, int nw) {
    __shared__ __align__(16) char smem[49152];
    const int b    = blockIdx.x;
    const int tid  = threadIdx.x;
    const int wave = tid >> 6;
    const int lane = tid & 63;
    const int g = lane >> 4;
    const int c = lane & 15;
    const int h = wave;

    char* Wq = smem + wave * 12288;
    char* Wk = Wq + 4096;
    char* Wv = Wq + 8192;
    char* Pp = Wq;

    bf16x8 xf[4][4];
    {
        const float* xb = x + (size_t)b * (NTOK * DIM);
        #pragma unroll
        for (int t = 0; t < 4; ++t) {
            const int tok = t * 16 + c;
            const bool ok = (tok < NTOK);
            const float* rp = xb + tok * DIM;
            #pragma unroll
            for (int ks = 0; ks < 4; ++ks) {
                f32x4 lo = ok ? *(const f32x4*)(rp + ks * 32 + g * 8)     : (f32x4){0.f,0.f,0.f,0.f};
                f32x4 hi = ok ? *(const f32x4*)(rp + ks * 32 + g * 8 + 4) : (f32x4){0.f,0.f,0.f,0.f};
                xf[t][ks] = cvt8(lo, hi);
            }
        }
    }
    {
        f32x4 acc[2][4];
        #pragma unroll
        for (int mtd = 0; mtd < 2; ++mtd) {
            const f32x4 qb4 = *(const f32x4*)(qkv_b + h * 32 + mtd * 16 + g * 4);
            #pragma unroll
            for (int nt = 0; nt < 4; ++nt) acc[mtd][nt] = qb4;
        }
        #pragma unroll
        for (int ks = 0; ks < 4; ++ks) {
            bf16x8 w0 = *(const bf16x8*)(qkvw + (h * 32 +  0 + c) * DIM + ks * 32 + g * 8);
            bf16x8 w1 = *(const bf16x8*)(qkvw + (h * 32 + 16 + c) * DIM + ks * 32 + g * 8);
            #pragma unroll
            for (int nt = 0; nt < 4; ++nt) {
                acc[0][nt] = __builtin_amdgcn_mfma_f32_16x16x32_bf16(w0, xf[nt][ks], acc[0][nt], 0, 0, 0);
                acc[1][nt] = __builtin_amdgcn_mfma_f32_16x16x32_bf16(w1, xf[nt][ks], acc[1][nt], 0, 0, 0);
            }
        }
        #pragma unroll
        for (int mtd = 0; mtd < 2; ++mtd)
            #pragma unroll
            for (int nt = 0; nt < 4; ++nt) {
                f32x4 a = acc[mtd][nt];
                bf16x4 pk = { (bfloat_t)(a[0]*SCALE), (bfloat_t)(a[1]*SCALE),
                              (bfloat_t)(a[2]*SCALE), (bfloat_t)(a[3]*SCALE) };
                const int byte = (nt*16 + c)*64 + (((2*mtd + (g>>1)) ^ (c&3)) << 4) + ((g&1) << 3);
                *(bf16x4*)(Wq + byte) = pk;
            }
    }
    {
        f32x4 acc[2][4];
        #pragma unroll
        for (int mtd = 0; mtd < 2; ++mtd) {
            const f32x4 kb4 = *(const f32x4*)(qkv_b + DIM + h * 32 + mtd * 16 + g * 4);
            #pragma unroll
            for (int nt = 0; nt < 4; ++nt) acc[mtd][nt] = kb4;
        }
        #pragma unroll
        for (int ks = 0; ks < 4; ++ks) {
            bf16x8 w0 = *(const bf16x8*)(qkvw + (DIM + h * 32 +  0 + c) * DIM + ks * 32 + g * 8);
            bf16x8 w1 = *(const bf16x8*)(qkvw + (DIM + h * 32 + 16 + c) * DIM + ks * 32 + g * 8);
            #pragma unroll
            for (int nt = 0; nt < 4; ++nt) {
                acc[0][nt] = __builtin_amdgcn_mfma_f32_16x16x32_bf16(w0, xf[nt][ks], acc[0][nt], 0, 0, 0);
                acc[1][nt] = __builtin_amdgcn_mfma_f32_16x16x32_bf16(w1, xf[nt][ks], acc[1][nt], 0, 0, 0);
            }
        }
        #pragma unroll
        for (int mtd = 0; mtd < 2; ++mtd)
            #pragma unroll
            for (int nt = 0; nt < 4; ++nt) {
                f32x4 a = acc[mtd][nt];
                bf16x4 pk = { (bfloat_t)a[0], (bfloat_t)a[1], (bfloat_t)a[2], (bfloat_t)a[3] };
                const int byte = (nt*16 + c)*64 + (((2*mtd + (g>>1)) ^ (c&3)) << 4) + ((g&1) << 3);
                *(bf16x4*)(Wk + byte) = pk;
            }
    }
    {
        f32x4 acc[4][2];
        #pragma unroll
        for (int nt = 0; nt < 2; ++nt) {
            const float vb = qkv_b[2 * DIM + h * 32 + nt * 16 + c];
            #pragma unroll
            for (int mt = 0; mt < 4; ++mt) acc[mt][nt] = (f32x4){vb, vb, vb, vb};
        }
        #pragma unroll
        for (int ks = 0; ks < 4; ++ks) {
            bf16x8 w0 = *(const bf16x8*)(qkvw + (2 * DIM + h * 32 +  0 + c) * DIM + ks * 32 + g * 8);
            bf16x8 w1 = *(const bf16x8*)(qkvw + (2 * DIM + h * 32 + 16 + c) * DIM + ks * 32 + g * 8);
            #pragma unroll
            for (int mt = 0; mt < 4; ++mt) {
                acc[mt][0] = __builtin_amdgcn_mfma_f32_16x16x32_bf16(xf[mt][ks], w0, acc[mt][0], 0, 0, 0);
                acc[mt][1] = __builtin_amdgcn_mfma_f32_16x16x32_bf16(xf[mt][ks], w1, acc[mt][1], 0, 0, 0);
            }
        }
        #pragma unroll
        for (int mt = 0; mt < 4; ++mt)
            #pragma unroll
            for (int nt = 0; nt < 2; ++nt) {
                f32x4 a = acc[mt][nt];
                bf16x4 pk = { (bfloat_t)a[0], (bfloat_t)a[1], (bfloat_t)a[2], (bfloat_t)a[3] };
                const int byte = (nt*16 + c)*128 + (((2*mt + (g>>1)) ^ (c&7)) << 4) + ((g&1) << 3);
                *(bf16x4*)(Wv + byte) = pk;
            }
    }
    float dinv[4];
    {
        const float* cw = cmb + (size_t)((b % nw) * NH + h) * 4096;
        f32x4 s[4][4];
        #pragma unroll
        for (int mtk = 0; mtk < 4; ++mtk)
            #pragma unroll
            for (int ntq = 0; ntq < 4; ++ntq)
                s[mtk][ntq] = *(const f32x4*)(cw + (ntq * 16 + c) * 64 + mtk * 16 + g * 4);
        bf16x8 kf[4], qf[4];
        #pragma unroll
        for (int t = 0; t < 4; ++t) {
            kf[t] = *(const bf16x8*)(Wk + (t*16 + c)*64 + ((g ^ (c&3)) << 4));
            qf[t] = *(const bf16x8*)(Wq + (t*16 + c)*64 + ((g ^ (c&3)) << 4));
        }
        #pragma unroll
        for (int mtk = 0; mtk < 4; ++mtk)
            #pragma unroll
            for (int ntq = 0; ntq < 4; ++ntq)
                s[mtk][ntq] = __builtin_amdgcn_mfma_f32_16x16x32_bf16(kf[mtk], qf[ntq], s[mtk][ntq], 0, 0, 0);
        #pragma unroll
        for (int ntq = 0; ntq < 4; ++ntq) {
            float m = s[0][ntq][0];
            #pragma unroll
            for (int mtk = 0; mtk < 4; ++mtk)
                #pragma unroll
                for (int r = 0; r < 4; ++r) m = fmaxf(m, s[mtk][ntq][r]);
            m = fmaxf(m, __shfl_xor(m, 16));
            m = fmaxf(m, __shfl_xor(m, 32));
            float sum = 0.f;
            #pragma unroll
            for (int mtk = 0; mtk < 4; ++mtk)
                #pragma unroll
                for (int r = 0; r < 4; ++r) {
                    float p = __expf(s[mtk][ntq][r] - m);
                    s[mtk][ntq][r] = p;
                    sum += p;
                }
            sum += __shfl_xor(sum, 16);
            sum += __shfl_xor(sum, 32);
            dinv[ntq] = 1.f / sum;
        }
        #pragma unroll
        for (int mtk = 0; mtk < 4; ++mtk)
            #pragma unroll
            for (int ntq = 0; ntq < 4; ++ntq) {
                f32x4 a = s[mtk][ntq];
                bf16x4 pk = { (bfloat_t)a[0], (bfloat_t)a[1], (bfloat_t)a[2], (bfloat_t)a[3] };
                const int byte = (ntq*16 + c)*128 + (((2*mtk + (g>>1)) ^ (c&7)) << 4) + ((g&1) << 3);
                *(bf16x4*)(Pp + byte) = pk;
            }
    }
    {
        f32x4 o[2][4];
        #pragma unroll
        for (int mtd = 0; mtd < 2; ++mtd)
            #pragma unroll
            for (int ntq = 0; ntq < 4; ++ntq) o[mtd][ntq] = (f32x4){0.f,0.f,0.f,0.f};
        #pragma unroll
        for (int ks = 0; ks < 2; ++ks) {
            bf16x8 vf[2], pf[4];
            #pragma unroll
            for (int mtd = 0; mtd < 2; ++mtd)
                vf[mtd] = *(const bf16x8*)(Wv + (mtd*16 + c)*128 + (((ks*4 + g) ^ (c&7)) << 4));
            #pragma unroll
            for (int ntq = 0; ntq < 4; ++ntq)
                pf[ntq] = *(const bf16x8*)(Pp + (ntq*16 + c)*128 + (((ks*4 + g) ^ (c&7)) << 4));
            #pragma unroll
            for (int mtd = 0; mtd < 2; ++mtd)
                #pragma unroll
                for (int ntq = 0; ntq < 4; ++ntq)
                    o[mtd][ntq] = __builtin_amdgcn_mfma_f32_16x16x32_bf16(vf[mtd], pf[ntq], o[mtd][ntq], 0, 0, 0);
        }
        #pragma unroll
        for (int mtd = 0; mtd < 2; ++mtd)
            #pragma unroll
            for (int ntq = 0; ntq < 4; ++ntq)
                #pragma unroll
                for (int r = 0; r < 4; ++r) o[mtd][ntq][r] *= dinv[ntq];
        __syncthreads();
        #pragma unroll
        for (int mtd = 0; mtd < 2; ++mtd)
            #pragma unroll
            for (int ntq = 0; ntq < 4; ++ntq) {
                f32x4 a = o[mtd][ntq];
                bf16x4 pk = { (bfloat_t)a[0], (bfloat_t)a[1], (bfloat_t)a[2], (bfloat_t)a[3] };
                const int byte = (ntq*16 + c)*256 + ((((h*4 + 2*mtd + (g>>1)) ^ c) & 15) << 4) + ((g&1) << 3);
                *(bf16x4*)(smem + byte) = pk;
            }
    }
    __syncthreads();
    {
        f32x4 po[2][4];
        #pragma unroll
        for (int mtO = 0; mtO < 2; ++mtO) {
            const f32x4 pb4 = *(const f32x4*)(proj_b + wave * 32 + mtO * 16 + g * 4);
            #pragma unroll
            for (int nt = 0; nt < 4; ++nt) po[mtO][nt] = pb4;
        }
        #pragma unroll
        for (int ks = 0; ks < 4; ++ks) {
            bf16x8 w0 = *(const bf16x8*)(projw + (wave * 32 +  0 + c) * DIM + ks * 32 + g * 8);
            bf16x8 w1 = *(const bf16x8*)(projw + (wave * 32 + 16 + c) * DIM + ks * 32 + g * 8);
            bf16x8 aof[4];
            #pragma unroll
            for (int nt = 0; nt < 4; ++nt)
                aof[nt] = *(const bf16x8*)(smem + (nt*16 + c)*256 + ((((ks*4 + g) ^ c) & 15) << 4));
            #pragma unroll
            for (int nt = 0; nt < 4; ++nt) {
                po[0][nt] = __builtin_amdgcn_mfma_f32_16x16x32_bf16(w0, aof[nt], po[0][nt], 0, 0, 0);
                po[1][nt] = __builtin_amdgcn_mfma_f32_16x16x32_bf16(w1, aof[nt], po[1][nt], 0, 0, 0);
            }
        }
        float* og = out + (size_t)b * (NTOK * DIM);
        #pragma unroll
        for (int nt = 0; nt < 4; ++nt) {
            const int tok = nt * 16 + c;
            if (tok < NTOK) {
                #pragma unroll
                for (int mtO = 0; mtO < 2; ++mtO)
                    *(f32x4*)(og + tok * DIM + wave * 32 + mtO * 16 + g * 4) = po[mtO][nt];
            }
        }
    }
}

extern "C" void kernel_launch(void* const* d_in, const int* in_sizes, int n_in,
                              void* d_out, int out_size, void* d_ws, size_t ws_size,
                              hipStream_t stream) {
    (void)n_in; (void)out_size;
    const float* x          = (const float*)d_in[0];
    const float* mask       = (const float*)d_in[1];
    const float* qkv_w      = (const float*)d_in[2];
    const float* qkv_b      = (const float*)d_in[3];
    const float* proj_w     = (const float*)d_in[4];
    const float* proj_b     = (const float*)d_in[5];
    const float* bias_table = (const float*)d_in[6];
    const int*   rel_index  = (const int*)d_in[7];
    float* out = (float*)d_out;

    const int B  = in_sizes[0] / (NTOK * DIM);
    const int nw = in_sizes[1] / (NTOK * NTOK);

    char* ws = (char*)d_ws;
    bfloat_t* qkvw_b  = (bfloat_t*)ws;                       // 98304 B
    bfloat_t* projw_b = (bfloat_t*)(ws + 98304);             // 32768 B
    float*    cmb     = (float*)(ws + 131072);               // nw*NH*64*64*4 B
    const size_t cmb_bytes = (size_t)nw * NH * 4096 * 4;
    const size_t off = 131072 + cmb_bytes;
    const size_t per = (size_t)B * NH * 64 * 32 * 2;         // q/k/vT each
    const size_t need = off + 3 * per;

    prep_weights<<<dim3((QKVN * DIM + 255) / 256), dim3(256), 0, stream>>>(qkv_w, proj_w, qkvw_b, projw_b);
    prep_cmb<<<dim3(nw * NH), dim3(256), 0, stream>>>(mask, bias_table, rel_index, cmb);

    if (ws_size >= need && (B % 2) == 0) {
        bfloat_t* qg  = (bfloat_t*)(ws + off);
        bfloat_t* kg  = (bfloat_t*)(ws + off + per);
        bfloat_t* vtg = (bfloat_t*)(ws + off + 2 * per);
        qkv_gemm<<<dim3(3, B / 2), dim3(256), 0, stream>>>(x, qkv_b, qkvw_b, qg, kg, vtg);
        attn_proj<<<dim3(B), dim3(256), 0, stream>>>(qg, kg, vtg, proj_b, projw_b, cmb, out, nw);
    } else {
        win_attn_fused<<<dim3(B), dim3(256), 0, stream>>>(x, qkv_b, proj_b, qkvw_b, projw_b, cmb, out, nw);
    }
}

// Round 4
// 161.323 us; speedup vs baseline: 1.7090x; 1.7090x over previous
//
#include <hip/hip_runtime.h>
#include <hip/hip_bf16.h>
#include <stdint.h>

#define NTOK 49
#define DIM  128
#define NH   4
#define QKVN 384
#define SCALE 0.17677669529663687f

typedef __bf16 bfloat_t;
typedef bfloat_t bf16x8 __attribute__((ext_vector_type(8)));
typedef bfloat_t bf16x4 __attribute__((ext_vector_type(4)));
typedef short    s16x4  __attribute__((ext_vector_type(4)));
typedef float    f32x4  __attribute__((ext_vector_type(4)));

#define MFMA32(a, b, c) __builtin_amdgcn_mfma_f32_16x16x32_bf16(a, b, c, 0, 0, 0)
#define MFMA16(a, b, c) __builtin_amdgcn_mfma_f32_16x16x16bf16_1k(a, b, c, 0, 0, 0)

static __device__ __forceinline__ bf16x4 pk4(f32x4 a) {
    bf16x4 r = { (bfloat_t)a[0], (bfloat_t)a[1], (bfloat_t)a[2], (bfloat_t)a[3] };
    return r;
}
static __device__ __forceinline__ s16x4 asi(bf16x4 v) {
    return __builtin_bit_cast(s16x4, v);
}

__global__ void prep_weights(const float* __restrict__ qkvw,
                             const float* __restrict__ projw,
                             bfloat_t* __restrict__ qkvw_b,
                             bfloat_t* __restrict__ projw_b) {
    int i = blockIdx.x * 256 + threadIdx.x;
    if (i < QKVN * DIM) qkvw_b[i] = (bfloat_t)qkvw[i];
    if (i < DIM * DIM)  projw_b[i] = (bfloat_t)projw[i];
}

// cmb[w][h][tok_q(64)][tok_k(64)] = bias + mask; tok_k>=49 -> -1e30; tok_q>=49 -> 0
__global__ void prep_cmb(const float* __restrict__ mask,
                         const float* __restrict__ bias_table,
                         const int* __restrict__ rel_index,
                         float* __restrict__ cmb) {
    int wh = blockIdx.x;            // w*NH + h
    int w = wh >> 2, h = wh & 3;
    for (int idx = threadIdx.x; idx < 4096; idx += 256) {
        int row = idx >> 6, col = idx & 63;   // row=tok_q, col=tok_k
        float v;
        if (col >= NTOK)      v = -1e30f;
        else if (row >= NTOK) v = 0.f;
        else v = bias_table[rel_index[row * NTOK + col] * NH + h]
               + mask[(w * NTOK + row) * NTOK + col];
        cmb[(size_t)wh * 4096 + idx] = v;
    }
}

// One block = one window; wave = head. All per-head tensors (q,k,v,P) live in
// registers: 16x16x16 MFMA operand layout == 16x16 C/D layout, so packed accs
// chain directly into the next MFMA. LDS: x tile 16KB (swizzled), overlaid by
// the 16KB ao exchange for proj. 3 barriers total.
__global__ __launch_bounds__(256, 4)
void win_attn(const float* __restrict__ x,
              const float* __restrict__ qkv_b,
              const float* __restrict__ proj_b,
              const bfloat_t* __restrict__ qkvw,
              const bfloat_t* __restrict__ projw,
              const float* __restrict__ cmb,
              float* __restrict__ out, int nw) {
    __shared__ __align__(16) char smem[16384];
    const int b    = blockIdx.x;
    const int tid  = threadIdx.x;
    const int wave = tid >> 6;
    const int lane = tid & 63;
    const int g = lane >> 4;
    const int c = lane & 15;
    const int h = wave;

    // ---- stage x -> LDS bf16 [64 tok][128 d], 16B-granule XOR swizzle ----
    {
        const float* xb = x + (size_t)b * (NTOK * DIM);
        #pragma unroll
        for (int i = 0; i < 8; ++i) {
            const int s = tid + i * 256;            // 0..2047 b64 slots
            const int row = s >> 5, col4 = (s & 31) * 4;
            f32x4 v = (row < NTOK) ? *(const f32x4*)(xb + row * DIM + col4)
                                   : (f32x4){0.f, 0.f, 0.f, 0.f};
            *(bf16x4*)(smem + row * 256 + ((col4 * 2) ^ ((row & 7) << 4))) = pk4(v);
        }
    }
    __syncthreads();

    // x A-frag (K=32): [tok=t*16+c][d = ks*32 + g*8 .. +7]
    #define LDX(t, ks) (*(const bf16x8*)(smem + ((t)*16 + c) * 256 + \
                        (((ks)*64 + g*16) ^ ((c & 7) << 4))))

    bf16x4 qp[2][4], kp[2][4], vp[4][2];   // packed frags, chunk layout = C/D layout

    // ---- q^T = Wq_h . x^T : D[m=d(2 tiles)][n=tok(4 tiles)] ----
    {
        f32x4 acc[2][4];
        #pragma unroll
        for (int mtd = 0; mtd < 2; ++mtd) {
            const f32x4 qb4 = *(const f32x4*)(qkv_b + h * 32 + mtd * 16 + g * 4);
            #pragma unroll
            for (int nt = 0; nt < 4; ++nt) acc[mtd][nt] = qb4;
        }
        #pragma unroll
        for (int ks = 0; ks < 4; ++ks) {
            bf16x8 w0 = *(const bf16x8*)(qkvw + (h * 32 +  0 + c) * DIM + ks * 32 + g * 8);
            bf16x8 w1 = *(const bf16x8*)(qkvw + (h * 32 + 16 + c) * DIM + ks * 32 + g * 8);
            #pragma unroll
            for (int nt = 0; nt < 4; ++nt) {
                bf16x8 a = LDX(nt, ks);
                acc[0][nt] = MFMA32(w0, a, acc[0][nt]);
                acc[1][nt] = MFMA32(w1, a, acc[1][nt]);
            }
        }
        #pragma unroll
        for (int ds = 0; ds < 2; ++ds)
            #pragma unroll
            for (int nt = 0; nt < 4; ++nt) {
                f32x4 a = acc[ds][nt];
                f32x4 sc = { a[0]*SCALE, a[1]*SCALE, a[2]*SCALE, a[3]*SCALE };
                qp[ds][nt] = pk4(sc);
            }
    }

    // ---- k^T = Wk_h . x^T ----
    {
        f32x4 acc[2][4];
        #pragma unroll
        for (int mtd = 0; mtd < 2; ++mtd) {
            const f32x4 kb4 = *(const f32x4*)(qkv_b + DIM + h * 32 + mtd * 16 + g * 4);
            #pragma unroll
            for (int nt = 0; nt < 4; ++nt) acc[mtd][nt] = kb4;
        }
        #pragma unroll
        for (int ks = 0; ks < 4; ++ks) {
            bf16x8 w0 = *(const bf16x8*)(qkvw + (DIM + h * 32 +  0 + c) * DIM + ks * 32 + g * 8);
            bf16x8 w1 = *(const bf16x8*)(qkvw + (DIM + h * 32 + 16 + c) * DIM + ks * 32 + g * 8);
            #pragma unroll
            for (int nt = 0; nt < 4; ++nt) {
                bf16x8 a = LDX(nt, ks);
                acc[0][nt] = MFMA32(w0, a, acc[0][nt]);
                acc[1][nt] = MFMA32(w1, a, acc[1][nt]);
            }
        }
        #pragma unroll
        for (int ds = 0; ds < 2; ++ds)
            #pragma unroll
            for (int nt = 0; nt < 4; ++nt) kp[ds][nt] = pk4(acc[ds][nt]);
    }

    // ---- v = x . Wv_h^T : D[m=tok(4 tiles)][n=d(2 tiles)] ----
    {
        f32x4 acc[4][2];
        #pragma unroll
        for (int nt = 0; nt < 2; ++nt) {
            const float vb = qkv_b[2 * DIM + h * 32 + nt * 16 + c];
            #pragma unroll
            for (int mt = 0; mt < 4; ++mt) acc[mt][nt] = (f32x4){vb, vb, vb, vb};
        }
        #pragma unroll
        for (int ks = 0; ks < 4; ++ks) {
            bf16x8 w0 = *(const bf16x8*)(qkvw + (2 * DIM + h * 32 +  0 + c) * DIM + ks * 32 + g * 8);
            bf16x8 w1 = *(const bf16x8*)(qkvw + (2 * DIM + h * 32 + 16 + c) * DIM + ks * 32 + g * 8);
            #pragma unroll
            for (int mt = 0; mt < 4; ++mt) {
                bf16x8 a = LDX(mt, ks);
                acc[mt][0] = MFMA32(a, w0, acc[mt][0]);
                acc[mt][1] = MFMA32(a, w1, acc[mt][1]);
            }
        }
        #pragma unroll
        for (int mt = 0; mt < 4; ++mt)
            #pragma unroll
            for (int nt = 0; nt < 2; ++nt) vp[mt][nt] = pk4(acc[mt][nt]);
    }

    // ---- S^T = k . q^T (K=16 MFMA, operands straight from qp/kp), softmax ----
    bf16x4 pp[4][4];         // packed P frags [mtk][ntq]
    float dinv[4];
    {
        const float* cw = cmb + (size_t)((b % nw) * NH + h) * 4096;
        #pragma unroll
        for (int ntq = 0; ntq < 4; ++ntq) {
            f32x4 s[4];
            #pragma unroll
            for (int mtk = 0; mtk < 4; ++mtk)
                s[mtk] = *(const f32x4*)(cw + (ntq * 16 + c) * 64 + mtk * 16 + g * 4);
            #pragma unroll
            for (int mtk = 0; mtk < 4; ++mtk) {
                s[mtk] = MFMA16(asi(kp[0][mtk]), asi(qp[0][ntq]), s[mtk]);
                s[mtk] = MFMA16(asi(kp[1][mtk]), asi(qp[1][ntq]), s[mtk]);
            }
            float m = s[0][0];
            #pragma unroll
            for (int mtk = 0; mtk < 4; ++mtk)
                #pragma unroll
                for (int r = 0; r < 4; ++r) m = fmaxf(m, s[mtk][r]);
            m = fmaxf(m, __shfl_xor(m, 16));
            m = fmaxf(m, __shfl_xor(m, 32));
            float sum = 0.f;
            #pragma unroll
            for (int mtk = 0; mtk < 4; ++mtk)
                #pragma unroll
                for (int r = 0; r < 4; ++r) {
                    float p = __expf(s[mtk][r] - m);
                    s[mtk][r] = p;
                    sum += p;
                }
            sum += __shfl_xor(sum, 16);
            sum += __shfl_xor(sum, 32);
            dinv[ntq] = 1.f / sum;
            #pragma unroll
            for (int mtk = 0; mtk < 4; ++mtk) pp[mtk][ntq] = pk4(s[mtk]);
        }
    }

    // ---- O^T = vT . P^T (K=16 MFMA, operands straight from vp/pp) ----
    f32x4 o[2][4];
    {
        #pragma unroll
        for (int mtd = 0; mtd < 2; ++mtd)
            #pragma unroll
            for (int ntq = 0; ntq < 4; ++ntq) o[mtd][ntq] = (f32x4){0.f, 0.f, 0.f, 0.f};
        #pragma unroll
        for (int mtk = 0; mtk < 4; ++mtk)
            #pragma unroll
            for (int mtd = 0; mtd < 2; ++mtd)
                #pragma unroll
                for (int ntq = 0; ntq < 4; ++ntq)
                    o[mtd][ntq] = MFMA16(asi(vp[mtk][mtd]), asi(pp[mtk][ntq]), o[mtd][ntq]);
        #pragma unroll
        for (int mtd = 0; mtd < 2; ++mtd)
            #pragma unroll
            for (int ntq = 0; ntq < 4; ++ntq)
                #pragma unroll
                for (int r = 0; r < 4; ++r) o[mtd][ntq][r] *= dinv[ntq];
    }

    __syncthreads();   // all waves done with x region; reuse as ao exchange
    // ao[tok][d] bf16, 16B-granule swizzle ^ (c&15)
    #pragma unroll
    for (int mtd = 0; mtd < 2; ++mtd)
        #pragma unroll
        for (int ntq = 0; ntq < 4; ++ntq) {
            const int byte = (ntq*16 + c)*256 + ((((h*4 + 2*mtd + (g>>1)) ^ c) & 15) << 4) + ((g&1) << 3);
            *(bf16x4*)(smem + byte) = pk4(o[mtd][ntq]);
        }
    __syncthreads();

    // ---- out^T = Wp . ao^T : wave owns 32 output cols; f32x4 stores ----
    {
        f32x4 po[2][4];
        #pragma unroll
        for (int mtO = 0; mtO < 2; ++mtO) {
            const f32x4 pb4 = *(const f32x4*)(proj_b + wave * 32 + mtO * 16 + g * 4);
            #pragma unroll
            for (int nt = 0; nt < 4; ++nt) po[mtO][nt] = pb4;
        }
        #pragma unroll
        for (int ks = 0; ks < 4; ++ks) {
            bf16x8 w0 = *(const bf16x8*)(projw + (wave * 32 +  0 + c) * DIM + ks * 32 + g * 8);
            bf16x8 w1 = *(const bf16x8*)(projw + (wave * 32 + 16 + c) * DIM + ks * 32 + g * 8);
            bf16x8 aof[4];
            #pragma unroll
            for (int nt = 0; nt < 4; ++nt)
                aof[nt] = *(const bf16x8*)(smem + (nt*16 + c)*256 + ((((ks*4 + g) ^ c) & 15) << 4));
            #pragma unroll
            for (int nt = 0; nt < 4; ++nt) {
                po[0][nt] = MFMA32(w0, aof[nt], po[0][nt]);
                po[1][nt] = MFMA32(w1, aof[nt], po[1][nt]);
            }
        }
        float* og = out + (size_t)b * (NTOK * DIM);
        #pragma unroll
        for (int nt = 0; nt < 4; ++nt) {
            const int tok = nt * 16 + c;
            if (tok < NTOK) {
                #pragma unroll
                for (int mtO = 0; mtO < 2; ++mtO)
                    *(f32x4*)(og + tok * DIM + wave * 32 + mtO * 16 + g * 4) = po[mtO][nt];
            }
        }
    }
    #undef LDX
}

extern "C" void kernel_launch(void* const* d_in, const int* in_sizes, int n_in,
                              void* d_out, int out_size, void* d_ws, size_t ws_size,
                              hipStream_t stream) {
    (void)n_in; (void)out_size; (void)ws_size;
    const float* x          = (const float*)d_in[0];
    const float* mask       = (const float*)d_in[1];
    const float* qkv_w      = (const float*)d_in[2];
    const float* qkv_b      = (const float*)d_in[3];
    const float* proj_w     = (const float*)d_in[4];
    const float* proj_b     = (const float*)d_in[5];
    const float* bias_table = (const float*)d_in[6];
    const int*   rel_index  = (const int*)d_in[7];
    float* out = (float*)d_out;

    char* ws = (char*)d_ws;
    bfloat_t* qkvw_b  = (bfloat_t*)ws;              // 98304 B
    bfloat_t* projw_b = (bfloat_t*)(ws + 98304);    // 32768 B
    float*    cmb     = (float*)(ws + 131072);      // nw*NH*64*64*4 B

    const int B  = in_sizes[0] / (NTOK * DIM);
    const int nw = in_sizes[1] / (NTOK * NTOK);

    prep_weights<<<dim3((QKVN * DIM + 255) / 256), dim3(256), 0, stream>>>(qkv_w, proj_w, qkvw_b, projw_b);
    prep_cmb<<<dim3(nw * NH), dim3(256), 0, stream>>>(mask, bias_table, rel_index, cmb);
    win_attn<<<dim3(B), dim3(256), 0, stream>>>(x, qkv_b, proj_b, qkvw_b, projw_b, cmb, out, nw);
}